// Round 11
// baseline (2293.884 us; speedup 1.0000x reference)
//
#include <hip/hip_runtime.h>

#define B_ 32
#define T_ 24
#define N_ 2048
#define D_ 64
#define K_ 32
#define H_ 16
#define NB 16
#define KP 128  // augmented K: 64 (W) + 64 (identity for +eb)

typedef __attribute__((ext_vector_type(8))) short bf16x8;
typedef __attribute__((ext_vector_type(4))) float f32x4;
typedef __attribute__((ext_vector_type(4))) int i32x4;

__device__ __forceinline__ unsigned short f2bf(float f) {
    unsigned int u = __float_as_uint(f);
    return (unsigned short)((u + 0x7FFFu + ((u >> 16) & 1u)) >> 16);
}

__device__ __forceinline__ int pack2(float a, float b) {
    return (int)((unsigned)f2bf(a) | ((unsigned)f2bf(b) << 16));
}

// M2 f32, lane-coalesced: M2[n>>4][t*24+t2][n&15] = sum_h ad[h][t]*ad[h][t2]
__global__ void k_prepM(const float* __restrict__ ne, const float* __restrict__ adj,
                        float* __restrict__ M2) {
    __shared__ float s_ne[K_];
    __shared__ float s_ad[H_ * T_];
    const int n = blockIdx.x;
    const int tid = threadIdx.x;  // 64 threads
    if (tid < K_) s_ne[tid] = ne[n * K_ + tid];
    __syncthreads();
    for (int f = tid; f < H_ * T_; f += 64) {
        const int h = f / T_, t = f % T_;
        float a = 0.f;
#pragma unroll
        for (int k = 0; k < K_; ++k) a += s_ne[k] * adj[(k * H_ + h) * T_ + t];
        s_ad[f] = a;
    }
    __syncthreads();
    float* dst = M2 + (size_t)(n >> 4) * (T_ * T_ * 16) + (n & 15);
    for (int m = tid; m < T_ * T_; m += 64) {
        const int t = m / T_, t2 = m % T_;
        float a = 0.f;
#pragma unroll
        for (int h = 0; h < H_; ++h) a += s_ad[h * T_ + t] * s_ad[h * T_ + t2];
        dst[m * 16] = a;
    }
}

// Wt[bt][o][i'] (bf16), i' in [0,128): i'<64 -> sum_k te*wp[k][i'][o]; i'>=64 -> (i'-64==o)
__global__ __launch_bounds__(256) void k_prepW(const float* __restrict__ te,
                                               const float* __restrict__ wp,
                                               const float* __restrict__ bp,
                                               unsigned short* __restrict__ Wt,
                                               float* __restrict__ bias) {
    const int bt = blockIdx.x;   // 0..B*T-1
    const int tid = threadIdx.x; // 256
    __shared__ float s_te[K_];
    __shared__ float s_W[D_ * D_];  // [i][o] f32
    if (tid < K_) s_te[tid] = te[bt * K_ + tid];
    __syncthreads();
    float4 acc[4] = {};
    for (int k = 0; k < K_; ++k) {
        const float tk = s_te[k];
        const float4* row = (const float4*)(wp + (size_t)k * (D_ * D_));
#pragma unroll
        for (int i = 0; i < 4; ++i) {
            float4 v = row[tid + i * 256];
            acc[i].x += tk * v.x; acc[i].y += tk * v.y;
            acc[i].z += tk * v.z; acc[i].w += tk * v.w;
        }
    }
    float4* sW4 = (float4*)s_W;
#pragma unroll
    for (int i = 0; i < 4; ++i) sW4[tid + i * 256] = acc[i];
    if (tid < D_) {
        float a = 0.f;
#pragma unroll
        for (int k = 0; k < K_; ++k) a += s_te[k] * bp[k * D_ + tid];
        bias[bt * D_ + tid] = a;
    }
    __syncthreads();
    // emit Wt[o][i'] bf16, augmented with identity block
    const int o = tid >> 2;          // 0..63
    const int i0 = (tid & 3) * 32;   // 0,32,64,96
    unsigned short* dst = Wt + (size_t)bt * (D_ * KP) + o * KP + i0;
#pragma unroll
    for (int j = 0; j < 32; j += 4) {
        const int i = i0 + j;
        ushort4 u;
        u.x = (i + 0 < 64) ? f2bf(s_W[(i + 0) * D_ + o])
                           : ((i + 0 - 64 == o) ? (unsigned short)0x3F80 : (unsigned short)0);
        u.y = (i + 1 < 64) ? f2bf(s_W[(i + 1) * D_ + o])
                           : ((i + 1 - 64 == o) ? (unsigned short)0x3F80 : (unsigned short)0);
        u.z = (i + 2 < 64) ? f2bf(s_W[(i + 2) * D_ + o])
                           : ((i + 2 - 64 == o) ? (unsigned short)0x3F80 : (unsigned short)0);
        u.w = (i + 3 < 64) ? f2bf(s_W[(i + 3) * D_ + o])
                           : ((i + 3 - 64 == o) ? (unsigned short)0x3F80 : (unsigned short)0);
        *(ushort4*)(dst + j) = u;
    }
}

// Fused, streaming, NO LDS / NO barriers.
// Block = (16-node tile, b), 256 threads / 4 waves; wave w, pass p -> t in [p*12+3w, +3).
// Lane (lr=n, lh=d-oct): mix reads eb f32 direct (coalesced), M from lane-coalesced M2.
// Phase 2: augmented MFMA K=128 (W;I) folds +eb; bias in C-init.
__global__ __launch_bounds__(256, 4) void k_fused(const float* __restrict__ eb,
                                                  const float* __restrict__ M2,
                                                  const unsigned short* __restrict__ Wt,
                                                  const float* __restrict__ bias,
                                                  float* __restrict__ out) {
    const int b = blockIdx.y;
    const int nbI = blockIdx.x;
    const int nb = nbI * NB;
    const int tid = threadIdx.x;
    const int wave = tid >> 6, lane = tid & 63;
    const int lr = lane & 15, lh = lane >> 4;

    const float* Mb = M2 + (size_t)nbI * (T_ * T_ * 16) + lr;        // + (t*24+tp)*16
    const float* ebn = eb + ((size_t)(b * T_) * N_ + nb + lr) * D_;  // + tp*N*D + d

    for (int pass = 0; pass < 2; ++pass) {
        const int tb = pass * 12 + wave * 3;

        float acc[3][16];
#pragma unroll
        for (int tt = 0; tt < 3; ++tt)
#pragma unroll
            for (int j = 0; j < 16; ++j) acc[tt][j] = 0.f;

#pragma unroll
        for (int tp = 0; tp < T_; ++tp) {
            const float m0 = Mb[((tb + 0) * T_ + tp) * 16];
            const float m1 = Mb[((tb + 1) * T_ + tp) * 16];
            const float m2 = Mb[((tb + 2) * T_ + tp) * 16];
            const float* ep = ebn + (size_t)tp * (N_ * D_);
            const float4 ea = *(const float4*)(ep + lh * 8);
            const float4 eb4 = *(const float4*)(ep + lh * 8 + 4);
            const float4 ec = *(const float4*)(ep + 32 + lh * 8);
            const float4 ed = *(const float4*)(ep + 32 + lh * 8 + 4);
            float ef[16] = {ea.x, ea.y, ea.z, ea.w, eb4.x, eb4.y, eb4.z, eb4.w,
                            ec.x, ec.y, ec.z, ec.w, ed.x, ed.y, ed.z, ed.w};
#pragma unroll
            for (int j = 0; j < 16; ++j) {
                acc[0][j] += m0 * ef[j];
                acc[1][j] += m1 * ef[j];
                acc[2][j] += m2 * ef[j];
            }
        }

#pragma unroll
        for (int tt = 0; tt < 3; ++tt) {
            const int t = tb + tt;
            const int bt = b * T_ + t;

            // A-frags kh0/kh1 from mix acc (ret, bf16)
            i32x4 a0v, a1v;
            a0v.x = pack2(acc[tt][0], acc[tt][1]);
            a0v.y = pack2(acc[tt][2], acc[tt][3]);
            a0v.z = pack2(acc[tt][4], acc[tt][5]);
            a0v.w = pack2(acc[tt][6], acc[tt][7]);
            a1v.x = pack2(acc[tt][8], acc[tt][9]);
            a1v.y = pack2(acc[tt][10], acc[tt][11]);
            a1v.z = pack2(acc[tt][12], acc[tt][13]);
            a1v.w = pack2(acc[tt][14], acc[tt][15]);
            const bf16x8 Af0 = __builtin_bit_cast(bf16x8, a0v);
            const bf16x8 Af1 = __builtin_bit_cast(bf16x8, a1v);

            // A-frags kh2/kh3 = eb[t] (identity path), L2-hot re-read
            const float* ept = ebn + (size_t)t * (N_ * D_);
            const float4 fa = *(const float4*)(ept + lh * 8);
            const float4 fb = *(const float4*)(ept + lh * 8 + 4);
            const float4 fc = *(const float4*)(ept + 32 + lh * 8);
            const float4 fd = *(const float4*)(ept + 32 + lh * 8 + 4);
            i32x4 a2v, a3v;
            a2v.x = pack2(fa.x, fa.y); a2v.y = pack2(fa.z, fa.w);
            a2v.z = pack2(fb.x, fb.y); a2v.w = pack2(fb.z, fb.w);
            a3v.x = pack2(fc.x, fc.y); a3v.y = pack2(fc.z, fc.w);
            a3v.z = pack2(fd.x, fd.y); a3v.w = pack2(fd.z, fd.w);
            const bf16x8 Af2 = __builtin_bit_cast(bf16x8, a2v);
            const bf16x8 Af3 = __builtin_bit_cast(bf16x8, a3v);

            const unsigned short* Wb = Wt + (size_t)bt * (D_ * KP);
            f32x4 C[4];
#pragma unroll
            for (int ot = 0; ot < 4; ++ot) {
                const float bv = bias[bt * D_ + ot * 16 + lr];
                C[ot][0] = bv; C[ot][1] = bv; C[ot][2] = bv; C[ot][3] = bv;
            }
#pragma unroll
            for (int ot = 0; ot < 4; ++ot) {
                const unsigned short* Wo = Wb + (ot * 16 + lr) * KP + lh * 8;
                const bf16x8 B0 = *(const bf16x8*)(Wo);
                const bf16x8 B1 = *(const bf16x8*)(Wo + 32);
                const bf16x8 B2 = *(const bf16x8*)(Wo + 64);
                const bf16x8 B3 = *(const bf16x8*)(Wo + 96);
                C[ot] = __builtin_amdgcn_mfma_f32_16x16x32_bf16(Af0, B0, C[ot], 0, 0, 0);
                C[ot] = __builtin_amdgcn_mfma_f32_16x16x32_bf16(Af1, B1, C[ot], 0, 0, 0);
                C[ot] = __builtin_amdgcn_mfma_f32_16x16x32_bf16(Af2, B2, C[ot], 0, 0, 0);
                C[ot] = __builtin_amdgcn_mfma_f32_16x16x32_bf16(Af3, B3, C[ot], 0, 0, 0);
            }

            float* obt = out + ((size_t)bt * N_ + nb) * D_;
#pragma unroll
            for (int ot = 0; ot < 4; ++ot) {
                const int o = ot * 16 + lr;
#pragma unroll
                for (int r = 0; r < 4; ++r) {
                    const int nn = lh * 4 + r;
                    float v = C[ot][r];
                    v = v >= 0.f ? v : 0.01f * v;
                    obt[(size_t)nn * D_ + o] = v;
                }
            }
        }
    }
}

extern "C" void kernel_launch(void* const* d_in, const int* in_sizes, int n_in,
                              void* d_out, int out_size, void* d_ws, size_t ws_size,
                              hipStream_t stream) {
    const float* eb  = (const float*)d_in[0];
    const float* ne  = (const float*)d_in[1];
    const float* te  = (const float*)d_in[2];
    const float* adj = (const float*)d_in[3];
    const float* wp  = (const float*)d_in[4];
    const float* bp  = (const float*)d_in[5];
    float* out = (float*)d_out;

    char* ws = (char*)d_ws;
    const size_t M_bytes  = (size_t)N_ * T_ * T_ * 4;        //  9,437,184 (f32)
    const size_t Wt_bytes = (size_t)B_ * T_ * D_ * KP * 2;   // 12,582,912 (bf16, K'=128)
    float* M2          = (float*)ws;
    unsigned short* Wt = (unsigned short*)(ws + M_bytes);
    float* bias        = (float*)(ws + M_bytes + Wt_bytes);

    k_prepM<<<N_, 64, 0, stream>>>(ne, adj, M2);
    k_prepW<<<B_ * T_, 256, 0, stream>>>(te, wp, bp, Wt, bias);
    k_fused<<<dim3(N_ / NB, B_), 256, 0, stream>>>(eb, M2, Wt, bias, out);
}

// Round 12
// 297.998 us; speedup vs baseline: 7.6977x; 7.6977x over previous
//
#include <hip/hip_runtime.h>

#define B_ 32
#define T_ 24
#define N_ 2048
#define D_ 64
#define K_ 32
#define H_ 16
#define NB 16

typedef __attribute__((ext_vector_type(8))) short bf16x8;
typedef __attribute__((ext_vector_type(4))) float f32x4;

__device__ __forceinline__ unsigned short f2bf(float f) {
    unsigned int u = __float_as_uint(f);
    return (unsigned short)((u + 0x7FFFu + ((u >> 16) & 1u)) >> 16);
}
__device__ __forceinline__ float bf2f(unsigned short h) {
    return __uint_as_float(((unsigned int)h) << 16);
}

// M2 f32, lane-coalesced: M2[n>>4][t*24+t2][n&15] = sum_h ad[h][t]*ad[h][t2]
__global__ void k_prepM(const float* __restrict__ ne, const float* __restrict__ adj,
                        float* __restrict__ M2) {
    __shared__ float s_ne[K_];
    __shared__ float s_ad[H_ * T_];
    const int n = blockIdx.x;
    const int tid = threadIdx.x;  // 64 threads
    if (tid < K_) s_ne[tid] = ne[n * K_ + tid];
    __syncthreads();
    for (int f = tid; f < H_ * T_; f += 64) {
        const int h = f / T_, t = f % T_;
        float a = 0.f;
#pragma unroll
        for (int k = 0; k < K_; ++k) a += s_ne[k] * adj[(k * H_ + h) * T_ + t];
        s_ad[f] = a;
    }
    __syncthreads();
    float* dst = M2 + (size_t)(n >> 4) * (T_ * T_ * 16) + (n & 15);
    for (int m = tid; m < T_ * T_; m += 64) {
        const int t = m / T_, t2 = m % T_;
        float a = 0.f;
#pragma unroll
        for (int h = 0; h < H_; ++h) a += s_ad[h * T_ + t] * s_ad[h * T_ + t2];
        dst[m * 16] = a;
    }
}

// Wt[bt][o][i] (bf16) = sum_k te[bt][k]*wp[k][i][o];  bias[bt][o] f32
__global__ __launch_bounds__(256) void k_prepW(const float* __restrict__ te,
                                               const float* __restrict__ wp,
                                               const float* __restrict__ bp,
                                               unsigned short* __restrict__ Wt,
                                               float* __restrict__ bias) {
    const int bt = blockIdx.x;   // 0..B*T-1
    const int tid = threadIdx.x; // 256
    __shared__ float s_te[K_];
    __shared__ float s_W[D_ * D_];  // [i][o] f32
    if (tid < K_) s_te[tid] = te[bt * K_ + tid];
    __syncthreads();
    float4 acc[4] = {};
    for (int k = 0; k < K_; ++k) {
        const float tk = s_te[k];
        const float4* row = (const float4*)(wp + (size_t)k * (D_ * D_));
#pragma unroll
        for (int i = 0; i < 4; ++i) {
            float4 v = row[tid + i * 256];
            acc[i].x += tk * v.x; acc[i].y += tk * v.y;
            acc[i].z += tk * v.z; acc[i].w += tk * v.w;
        }
    }
    float4* sW4 = (float4*)s_W;
#pragma unroll
    for (int i = 0; i < 4; ++i) sW4[tid + i * 256] = acc[i];
    if (tid < D_) {
        float a = 0.f;
#pragma unroll
        for (int k = 0; k < K_; ++k) a += s_te[k] * bp[k * D_ + tid];
        bias[bt * D_ + tid] = a;
    }
    __syncthreads();
    // transpose -> bf16: Wt[o][i]
    const int o = tid >> 2;
    const int i0 = (tid & 3) * 16;
    unsigned short* dst = Wt + (size_t)bt * (D_ * D_) + o * D_ + i0;
#pragma unroll
    for (int j = 0; j < 16; j += 4) {
        ushort4 u;
        u.x = f2bf(s_W[(i0 + j + 0) * D_ + o]);
        u.y = f2bf(s_W[(i0 + j + 1) * D_ + o]);
        u.z = f2bf(s_W[(i0 + j + 2) * D_ + o]);
        u.w = f2bf(s_W[(i0 + j + 3) * D_ + o]);
        *(ushort4*)(dst + j) = u;
    }
}

// load chunk-C element F (float4) of eb into GV
#define EBLD(F, C, GV)                                                      \
    {                                                                       \
        const int f_ = (F);                                                 \
        const int t_ = ((C) * 8) + (f_ >> 8);                               \
        const int rem_ = f_ & 255;                                          \
        const int n_ = rem_ >> 4;                                           \
        const int d0_ = (rem_ & 15) * 4;                                    \
        GV = *(const float4*)(ebb + ((size_t)t_ * N_ + nb + n_) * D_ + d0_);\
    }
// write GV (cvt to bf16, swizzled) into s_eb
#define EBST(F, C, GV)                                                      \
    {                                                                       \
        const int f_ = (F);                                                 \
        const int t_ = ((C) * 8) + (f_ >> 8);                               \
        const int rem_ = f_ & 255;                                          \
        const int n_ = rem_ >> 4;                                           \
        const int d0_ = (rem_ & 15) * 4;                                    \
        ushort4 u_;                                                         \
        u_.x = f2bf(GV.x); u_.y = f2bf(GV.y);                               \
        u_.z = f2bf(GV.z); u_.w = f2bf(GV.w);                               \
        *(ushort4*)((char*)s_eb + t_ * 2048 + n_ * 128 +                    \
                    ((d0_ * 2) ^ ((n_ & 7) << 4))) = u_;                    \
    }
// mix one chunk (8 tp) into acc[3][16]
#define MIXCHUNK(C)                                                         \
    _Pragma("unroll")                                                       \
    for (int tpl = 0; tpl < 8; ++tpl) {                                     \
        const int tp = (C) * 8 + tpl;                                       \
        const float m0 = Mb[((tb + 0) * T_ + tp) * 16];                     \
        const float m1 = Mb[((tb + 1) * T_ + tp) * 16];                     \
        const float m2 = Mb[((tb + 2) * T_ + tp) * 16];                     \
        const char* rowp = ebase + (tp * NB + lr) * 128;                    \
        const bf16x8 e0 = *(const bf16x8*)(rowp + ((lh * 16) ^ sw));        \
        const bf16x8 e1 = *(const bf16x8*)(rowp + (((lh + 4) * 16) ^ sw));  \
        float ef[16];                                                       \
        _Pragma("unroll")                                                   \
        for (int j = 0; j < 8; ++j) {                                       \
            ef[j] = bf2f((unsigned short)e0[j]);                            \
            ef[8 + j] = bf2f((unsigned short)e1[j]);                        \
        }                                                                   \
        _Pragma("unroll")                                                   \
        for (int j = 0; j < 16; ++j) {                                      \
            acc[0][j] += m0 * ef[j];                                        \
            acc[1][j] += m1 * ef[j];                                        \
            acc[2][j] += m2 * ef[j];                                        \
        }                                                                   \
    }

// Fused, pipelined staging: 512 threads / 8 waves, wave w owns t in [3w,3w+3).
// Chunked eb staging (3 x 8tp) overlapped with mix (issue-early / write-late).
__global__ __launch_bounds__(512, 2) void k_fused(const float* __restrict__ eb,
                                                  const float* __restrict__ M2,
                                                  const unsigned short* __restrict__ Wt,
                                                  const float* __restrict__ bias,
                                                  float* __restrict__ out) {
    const int b = blockIdx.y;
    const int nbI = blockIdx.x;
    const int nb = nbI * NB;
    const int tid = threadIdx.x;
    const int wave = tid >> 6, lane = tid & 63;
    const int lr = lane & 15, lh = lane >> 4;

    __shared__ unsigned short s_eb[T_ * NB * D_];  // 49152 B, [t][n][d] swizzled

    const float* ebb = eb + (size_t)(b * T_) * N_ * D_;
    const float* Mb = M2 + (size_t)nbI * (T_ * T_ * 16) + lr;
    const char* ebase = (const char*)s_eb;
    const int sw = (lr & 7) << 4;
    const int tb = wave * 3;

    float acc[3][16];
#pragma unroll
    for (int tt = 0; tt < 3; ++tt)
#pragma unroll
        for (int j = 0; j < 16; ++j) acc[tt][j] = 0.f;

    float4 g0, g1, g2, g3;
    // chunk 0: plain stage
    EBLD(tid, 0, g0) EBLD(tid + 512, 0, g1) EBLD(tid + 1024, 0, g2) EBLD(tid + 1536, 0, g3)
    EBST(tid, 0, g0) EBST(tid + 512, 0, g1) EBST(tid + 1024, 0, g2) EBST(tid + 1536, 0, g3)
    __syncthreads();

    // iter 0: issue chunk1, mix chunk0, write chunk1
    EBLD(tid, 1, g0) EBLD(tid + 512, 1, g1) EBLD(tid + 1024, 1, g2) EBLD(tid + 1536, 1, g3)
    MIXCHUNK(0)
    EBST(tid, 1, g0) EBST(tid + 512, 1, g1) EBST(tid + 1024, 1, g2) EBST(tid + 1536, 1, g3)
    __syncthreads();

    // iter 1: issue chunk2, mix chunk1, write chunk2
    EBLD(tid, 2, g0) EBLD(tid + 512, 2, g1) EBLD(tid + 1024, 2, g2) EBLD(tid + 1536, 2, g3)
    MIXCHUNK(1)
    EBST(tid, 2, g0) EBST(tid + 512, 2, g1) EBST(tid + 1024, 2, g2) EBST(tid + 1536, 2, g3)
    __syncthreads();

    // iter 2: mix chunk2
    MIXCHUNK(2)

    // convert to MFMA A-fragments: lane holds ret[t][n=lr][lh*8+j] and [32+lh*8+j]
    bf16x8 Af[3][2];
#pragma unroll
    for (int tt = 0; tt < 3; ++tt)
#pragma unroll
        for (int j = 0; j < 8; ++j) {
            Af[tt][0][j] = (short)f2bf(acc[tt][j]);
            Af[tt][1][j] = (short)f2bf(acc[tt][8 + j]);
        }

#pragma unroll
    for (int tt = 0; tt < 3; ++tt) {
        const int t = tb + tt;
        const int bt = b * T_ + t;
        const unsigned short* Wb = Wt + (size_t)bt * (D_ * D_);
        f32x4 C[4] = {};
#pragma unroll
        for (int ot = 0; ot < 4; ++ot) {
            const bf16x8 B0 = *(const bf16x8*)(Wb + (ot * 16 + lr) * D_ + lh * 8);
            const bf16x8 B1 = *(const bf16x8*)(Wb + (ot * 16 + lr) * D_ + 32 + lh * 8);
            C[ot] = __builtin_amdgcn_mfma_f32_16x16x32_bf16(Af[tt][0], B0, C[ot], 0, 0, 0);
            C[ot] = __builtin_amdgcn_mfma_f32_16x16x32_bf16(Af[tt][1], B1, C[ot], 0, 0, 0);
        }
        float bv[4];
#pragma unroll
        for (int ot = 0; ot < 4; ++ot) bv[ot] = bias[bt * D_ + ot * 16 + lr];

        float* obt = out + ((size_t)bt * N_ + nb) * D_;
#pragma unroll
        for (int r = 0; r < 4; ++r) {
            const int nn = lh * 4 + r;  // node within tile (C-row)
            const char* erow = ebase + (t * NB + nn) * 128;
            const int swn = (nn & 7) << 4;
#pragma unroll
            for (int ot = 0; ot < 4; ++ot) {
                const int o = ot * 16 + lr;  // C-col
                const unsigned short eu =
                    *(const unsigned short*)(erow + ((o * 2) ^ swn));
                float v = C[ot][r] + bv[ot] + bf2f(eu);
                v = v >= 0.f ? v : 0.01f * v;
                obt[(size_t)nn * D_ + o] = v;
            }
        }
    }
}

extern "C" void kernel_launch(void* const* d_in, const int* in_sizes, int n_in,
                              void* d_out, int out_size, void* d_ws, size_t ws_size,
                              hipStream_t stream) {
    const float* eb  = (const float*)d_in[0];
    const float* ne  = (const float*)d_in[1];
    const float* te  = (const float*)d_in[2];
    const float* adj = (const float*)d_in[3];
    const float* wp  = (const float*)d_in[4];
    const float* bp  = (const float*)d_in[5];
    float* out = (float*)d_out;

    char* ws = (char*)d_ws;
    const size_t M_bytes  = (size_t)N_ * T_ * T_ * 4;       // 4,718,592 (f32)
    const size_t Wt_bytes = (size_t)B_ * T_ * D_ * D_ * 2;  // 6,291,456
    float* M2          = (float*)ws;
    unsigned short* Wt = (unsigned short*)(ws + M_bytes);
    float* bias        = (float*)(ws + M_bytes + Wt_bytes);

    k_prepM<<<N_, 64, 0, stream>>>(ne, adj, M2);
    k_prepW<<<B_ * T_, 256, 0, stream>>>(te, wp, bp, Wt, bias);
    k_fused<<<dim3(N_ / NB, B_), 512, 0, stream>>>(eb, M2, Wt, bias, out);
}